// Round 2
// baseline (393.099 us; speedup 1.0000x reference)
//
#include <hip/hip_runtime.h>
#include <stdint.h>

typedef unsigned short u16;
typedef __bf16 bf16x8 __attribute__((ext_vector_type(8)));
typedef float f32x4 __attribute__((ext_vector_type(4)));

__device__ __forceinline__ float bf2f(u16 u) {
  union { unsigned int i; float f; } v; v.i = ((unsigned int)u) << 16; return v.f;
}
__device__ __forceinline__ u16 f2bf(float f) {
  union { float f; unsigned int i; } v; v.f = f;
  unsigned int r = v.i + 0x7fffu + ((v.i >> 16) & 1u);
  return (u16)(r >> 16);
}
// async global->LDS, 16B per lane. LDS dest is wave-uniform base + lane*16.
__device__ __forceinline__ void ld16(const void* g, void* l) {
  __builtin_amdgcn_global_load_lds(
      (const __attribute__((address_space(1))) unsigned int*)g,
      (__attribute__((address_space(3))) unsigned int*)l, 16, 0, 0);
}

// fp32 -> bf16 cast of x + 5 weight matrices, one launch.
// sizes (elems): x 4M, wq 4M, wk 1M, wv 1M, wo 4M, wg 4M -> 18432 blocks x 1024 elems.
__global__ __launch_bounds__(256) void k_cast(
    const float* __restrict__ s0, u16* __restrict__ d0,
    const float* __restrict__ s1, u16* __restrict__ d1,
    const float* __restrict__ s2, u16* __restrict__ d2,
    const float* __restrict__ s3, u16* __restrict__ d3,
    const float* __restrict__ s4, u16* __restrict__ d4,
    const float* __restrict__ s5, u16* __restrict__ d5)
{
  int b = blockIdx.x;
  const float* s; u16* d;
  if (b < 4096)       { s = s0; d = d0; }
  else if (b < 8192)  { s = s1; d = d1; b -= 4096; }
  else if (b < 9216)  { s = s2; d = d2; b -= 8192; }
  else if (b < 10240) { s = s3; d = d3; b -= 9216; }
  else if (b < 14336) { s = s4; d = d4; b -= 10240; }
  else                { s = s5; d = d5; b -= 14336; }
  const int i = (b * 256 + threadIdx.x) * 4;
  const float4 v = *(const float4*)(s + i);
  ushort4 o;
  o.x = f2bf(v.x); o.y = f2bf(v.y); o.z = f2bf(v.z); o.w = f2bf(v.w);
  *(ushort4*)(d + i) = o;
}

// C[128 x 128] = A[128 x K] * B[128 x K]^T  (both K-contiguous bf16).
// Block 256 threads = 4 waves; wave w -> 64x64 quadrant; 16x16x32 MFMA; BK=32.
template <typename OT>
__device__ __forceinline__ void gemm_body(
    const u16* __restrict__ A, int lda,
    const u16* __restrict__ B, int ldb,
    OT* __restrict__ C, int ldc, int K,
    u16* As, u16* Bs)
{
  const int tid = threadIdx.x;
  const int wave = tid >> 6, lane = tid & 63;
  const int lrow = lane >> 2;            // 4 lanes per 32-elem row
  const int lcol = (lane & 3) * 8;
  const int wrow = (wave >> 1) * 64, wcol = (wave & 1) * 64;
  const int fr = lane & 15, fq = (lane >> 4) * 8;

  f32x4 acc[4][4];
  const f32x4 z = {0.f, 0.f, 0.f, 0.f};
  for (int i = 0; i < 4; i++) for (int j = 0; j < 4; j++) acc[i][j] = z;

  const u16* Ag = A + (size_t)(wave * 32 + lrow) * lda + lcol;
  const u16* Bg = B + (size_t)(wave * 32 + lrow) * ldb + lcol;
  u16* Asw = As + wave * 1024;
  u16* Bsw = Bs + wave * 1024;

  for (int k0 = 0; k0 < K; k0 += 32) {
    ld16(Ag + k0, Asw);
    ld16(Ag + k0 + (size_t)16 * lda, Asw + 512);
    ld16(Bg + k0, Bsw);
    ld16(Bg + k0 + (size_t)16 * ldb, Bsw + 512);
    __syncthreads();   // drains vmcnt (global_load_lds) before ds_read
    bf16x8 af[4], bfr[4];
    for (int i = 0; i < 4; i++) af[i]  = *(const bf16x8*)&As[(wrow + i * 16 + fr) * 32 + fq];
    for (int i = 0; i < 4; i++) bfr[i] = *(const bf16x8*)&Bs[(wcol + i * 16 + fr) * 32 + fq];
    for (int mi = 0; mi < 4; mi++)
      for (int ni = 0; ni < 4; ni++)
        acc[mi][ni] = __builtin_amdgcn_mfma_f32_16x16x32_bf16(af[mi], bfr[ni], acc[mi][ni], 0, 0, 0);
    __syncthreads();
  }
  const int er = (lane >> 4) * 4, ec = lane & 15;
  for (int mi = 0; mi < 4; mi++)
    for (int ni = 0; ni < 4; ni++)
      for (int r = 0; r < 4; r++) {
        const float v = acc[mi][ni][r];
        OT* p = C + (size_t)(wrow + mi * 16 + er + r) * ldc + wcol + ni * 16 + ec;
        if constexpr (sizeof(OT) == 2) *p = (OT)f2bf(v); else *p = (OT)v;
      }
}

// Fused QKVG projection: out[s][0:2048]=q, [2048:2560]=k, [2560:3072]=v, [3072:5120]=g
__global__ __launch_bounds__(256) void k_gemm_qkvg(
    const u16* __restrict__ x, const u16* __restrict__ wq, const u16* __restrict__ wk,
    const u16* __restrict__ wv, const u16* __restrict__ wg, u16* __restrict__ out)
{
  __shared__ __align__(16) u16 As[128 * 32];
  __shared__ __align__(16) u16 Bs[128 * 32];
  const int m0 = blockIdx.x * 128;
  const int c0 = blockIdx.y * 128;
  const u16* B; int br;
  if (c0 < 2048)      { B = wq; br = c0; }
  else if (c0 < 2560) { B = wk; br = c0 - 2048; }
  else if (c0 < 3072) { B = wv; br = c0 - 2560; }
  else                { B = wg; br = c0 - 3072; }
  gemm_body<u16>(x + (size_t)m0 * 2048, 2048, B + (size_t)br * 2048, 2048,
                 out + (size_t)m0 * 5120 + c0, 5120, 2048, As, Bs);
}

__global__ __launch_bounds__(256) void k_gemm_out(
    const u16* __restrict__ a, const u16* __restrict__ wo, float* __restrict__ out)
{
  __shared__ __align__(16) u16 As[128 * 32];
  __shared__ __align__(16) u16 Bs[128 * 32];
  const int m0 = blockIdx.x * 128;
  const int c0 = blockIdx.y * 128;
  gemm_body<float>(a + (size_t)m0 * 2048, 2048, wo + (size_t)c0 * 2048, 2048,
                   out + (size_t)m0 * 2048 + c0, 2048, 2048, As, Bs);
}

// RoPE + per-head RMSNorm, in-place on q and k regions of qkvg (bf16).
// cos/sin/qn/kn are fp32 inputs. One wave per (s, head); lanes 0..31 own a pair.
__global__ __launch_bounds__(256) void k_rope_norm(
    u16* __restrict__ qkvg, const float* __restrict__ cosp, const float* __restrict__ sinp,
    const float* __restrict__ qn, const float* __restrict__ kn)
{
  const int wid = (blockIdx.x * 256 + threadIdx.x) >> 6;
  const int lane = threadIdx.x & 63;
  const int s = wid / 40, h = wid - s * 40;
  u16* base; const float* wn;
  if (h < 32) { base = qkvg + (size_t)s * 5120 + h * 64;                wn = qn; }
  else        { base = qkvg + (size_t)s * 5120 + 2048 + (h - 32) * 64; wn = kn; }
  const int j = lane;
  float o0 = 0.f, o1 = 0.f;
  const bool act = lane < 32;
  if (act) {
    const unsigned int u = *(const unsigned int*)(base + 2 * j);
    const float xr = bf2f((u16)(u & 0xffffu)), xi = bf2f((u16)(u >> 16));
    const float c = cosp[s * 32 + j], sn = sinp[s * 32 + j];
    o0 = xr * c - xi * sn;
    o1 = xr * sn + xi * c;
  }
  float ss = o0 * o0 + o1 * o1;
  for (int m = 1; m <= 16; m <<= 1) ss += __shfl_xor(ss, m, 64);
  if (act) {
    const float inv = rsqrtf(ss * (1.0f / 64.0f) + 1e-6f);
    const u16 r0 = f2bf(o0 * inv * wn[2 * j]);
    const u16 r1 = f2bf(o1 * inv * wn[2 * j + 1]);
    *(unsigned int*)(base + 2 * j) = (unsigned int)r0 | ((unsigned int)r1 << 16);
  }
}

// v[s][g*64+d] -> vt[(g*64+d)][s]
__global__ __launch_bounds__(256) void k_vtrans(const u16* __restrict__ qkvg, u16* __restrict__ vt)
{
  const int idx = blockIdx.x * 256 + threadIdx.x;   // gd*2048 + s
  const int s = idx & 2047, gd = idx >> 11;
  vt[idx] = qkvg[(size_t)s * 5120 + 2560 + gd];
}

// Flash attention, causal GQA. Block = (q-tile of 64 rows, head). 4 waves,
// wave w owns S/O rows w*16..w*16+16. Sigmoid gating fused in epilogue.
__global__ __launch_bounds__(256) void k_attn(
    const u16* __restrict__ qkvg, const u16* __restrict__ vt, u16* __restrict__ aout)
{
  __shared__ __align__(16) u16 Qs[64 * 64];
  __shared__ __align__(16) u16 Ks[64 * 64];
  __shared__ __align__(16) u16 Vs[64 * 64];   // V^T tile: [hd][key]
  __shared__ __align__(16) u16 Ps[64 * 64];
  const int qt = blockIdx.x, h = blockIdx.y, g = h >> 2;
  const int q0 = qt * 64;
  const int tid = threadIdx.x, wave = tid >> 6, lane = tid & 63;
  const int rr = lane >> 3, cc = (lane & 7) * 8;   // staging: 8 lanes per 64-elem row
  const int fr = lane & 15, fq = (lane >> 4) * 8;  // MFMA fragment addressing

  {
    const u16* Qg = qkvg + (size_t)(q0 + wave * 16 + rr) * 5120 + h * 64 + cc;
    ld16(Qg, Qs + wave * 1024);
    ld16(Qg + (size_t)8 * 5120, Qs + wave * 1024 + 512);
  }

  f32x4 o[4];
  const f32x4 z = {0.f, 0.f, 0.f, 0.f};
  for (int i = 0; i < 4; i++) o[i] = z;
  float mrow[4], lrow[4];
  for (int r = 0; r < 4; r++) { mrow[r] = -1e30f; lrow[r] = 0.f; }

  for (int t = 0; t <= qt; ++t) {
    const u16* Kg = qkvg + (size_t)(t * 64 + wave * 16 + rr) * 5120 + 2048 + g * 64 + cc;
    ld16(Kg, Ks + wave * 1024);
    ld16(Kg + (size_t)8 * 5120, Ks + wave * 1024 + 512);
    const u16* Vg = vt + (size_t)(g * 64 + wave * 16 + rr) * 2048 + t * 64 + cc;
    ld16(Vg, Vs + wave * 1024);
    ld16(Vg + (size_t)8 * 2048, Vs + wave * 1024 + 512);
    __syncthreads();

    // S = Q K^T (rows wave*16..+16, 64 keys)
    f32x4 sc[4];
    for (int i = 0; i < 4; i++) sc[i] = z;
    for (int k0 = 0; k0 < 64; k0 += 32) {
      const bf16x8 aq = *(const bf16x8*)&Qs[(wave * 16 + fr) * 64 + k0 + fq];
      for (int ni = 0; ni < 4; ni++) {
        const bf16x8 bk = *(const bf16x8*)&Ks[(ni * 16 + fr) * 64 + k0 + fq];
        sc[ni] = __builtin_amdgcn_mfma_f32_16x16x32_bf16(aq, bk, sc[ni], 0, 0, 0);
      }
    }

    // online softmax; C/D layout: row=(lane>>4)*4+r, col=ni*16+(lane&15)
    const int rbase = q0 + wave * 16 + (lane >> 4) * 4;
    for (int r = 0; r < 4; r++) {
      float sv[4];
      float mx = -1e30f;
      for (int ni = 0; ni < 4; ni++) {
        float s = sc[ni][r] * 0.125f;
        const int kc = t * 64 + ni * 16 + (lane & 15);
        if (kc > rbase + r) s = -1e30f;    // causal mask
        sv[ni] = s;
        mx = fmaxf(mx, s);
      }
      for (int m = 1; m <= 8; m <<= 1) mx = fmaxf(mx, __shfl_xor(mx, m, 64));
      const float mnew = fmaxf(mrow[r], mx);
      const float alpha = __expf(mrow[r] - mnew);
      mrow[r] = mnew;
      float ps = 0.f;
      for (int ni = 0; ni < 4; ni++) {
        const float p = __expf(sv[ni] - mnew);
        ps += p;
        Ps[(size_t)(wave * 16 + (lane >> 4) * 4 + r) * 64 + ni * 16 + (lane & 15)] = f2bf(p);
      }
      for (int m = 1; m <= 8; m <<= 1) ps += __shfl_xor(ps, m, 64);
      lrow[r] = lrow[r] * alpha + ps;
      for (int ni = 0; ni < 4; ni++) o[ni][r] *= alpha;
    }
    __syncthreads();   // P visible before PV

    // O += P @ V  (A from Ps rows, B from Vs = V^T[hd][key])
    for (int k0 = 0; k0 < 64; k0 += 32) {
      const bf16x8 ap = *(const bf16x8*)&Ps[(wave * 16 + fr) * 64 + k0 + fq];
      for (int ni = 0; ni < 4; ni++) {
        const bf16x8 bv = *(const bf16x8*)&Vs[(ni * 16 + fr) * 64 + k0 + fq];
        o[ni] = __builtin_amdgcn_mfma_f32_16x16x32_bf16(ap, bv, o[ni], 0, 0, 0);
      }
    }
    __syncthreads();   // Vs/Ps dead before next staging
  }

  for (int r = 0; r < 4; r++) {
    const int row = q0 + wave * 16 + (lane >> 4) * 4 + r;
    const float invl = 1.0f / lrow[r];
    for (int ni = 0; ni < 4; ni++) {
      const int col = h * 64 + ni * 16 + (lane & 15);
      const float gv = bf2f(qkvg[(size_t)row * 5120 + 3072 + col]);
      const float sig = 1.0f / (1.0f + __expf(-gv));
      aout[(size_t)row * 2048 + col] = f2bf(o[ni][r] * invl * sig);
    }
  }
}

extern "C" void kernel_launch(void* const* d_in, const int* in_sizes, int n_in,
                              void* d_out, int out_size, void* d_ws, size_t ws_size,
                              hipStream_t stream)
{
  const float* x  = (const float*)d_in[0];
  const float* cs = (const float*)d_in[1];
  const float* sn = (const float*)d_in[2];
  const float* wq = (const float*)d_in[3];
  const float* wk = (const float*)d_in[4];
  const float* wv = (const float*)d_in[5];
  const float* wo = (const float*)d_in[6];
  const float* wg = (const float*)d_in[7];
  const float* qn = (const float*)d_in[8];
  const float* kn = (const float*)d_in[9];
  float* out = (float*)d_out;

  u16* xb   = (u16*)d_ws;                      // 4M elems
  u16* wqb  = xb  + (size_t)4194304;           // 4M
  u16* wkb  = wqb + (size_t)4194304;           // 1M
  u16* wvb  = wkb + (size_t)1048576;           // 1M
  u16* wob  = wvb + (size_t)1048576;           // 4M
  u16* wgb  = wob + (size_t)4194304;           // 4M
  u16* qkvg = wgb + (size_t)4194304;           // 2048*5120
  u16* vt   = qkvg + (size_t)2048 * 5120;      // 512*2048
  u16* aws  = vt   + (size_t)512 * 2048;       // 2048*2048

  k_cast<<<dim3(18432), 256, 0, stream>>>(x, xb, wq, wqb, wk, wkb, wv, wvb, wo, wob, wg, wgb);
  k_gemm_qkvg<<<dim3(16, 40), 256, 0, stream>>>(xb, wqb, wkb, wvb, wgb, qkvg);
  k_rope_norm<<<dim3(2048 * 40 / 4), 256, 0, stream>>>(qkvg, cs, sn, qn, kn);
  k_vtrans<<<dim3(512 * 2048 / 256), 256, 0, stream>>>(qkvg, vt);
  k_attn<<<dim3(32, 32), 256, 0, stream>>>(qkvg, vt, aws);
  k_gemm_out<<<dim3(16, 16), 256, 0, stream>>>(aws, wob, out);
}

// Round 3
// 382.716 us; speedup vs baseline: 1.0271x; 1.0271x over previous
//
#include <hip/hip_runtime.h>
#include <stdint.h>

typedef unsigned short u16;
typedef __bf16 bf16x8 __attribute__((ext_vector_type(8)));
typedef float f32x4 __attribute__((ext_vector_type(4)));

__device__ __forceinline__ float bf2f(u16 u) {
  union { unsigned int i; float f; } v; v.i = ((unsigned int)u) << 16; return v.f;
}
__device__ __forceinline__ u16 f2bf(float f) {
  union { float f; unsigned int i; } v; v.f = f;
  unsigned int r = v.i + 0x7fffu + ((v.i >> 16) & 1u);
  return (u16)(r >> 16);
}
// async global->LDS, 16B per lane. LDS dest is wave-uniform base + lane*16.
__device__ __forceinline__ void ld16(const void* g, void* l) {
  __builtin_amdgcn_global_load_lds(
      (const __attribute__((address_space(1))) unsigned int*)g,
      (__attribute__((address_space(3))) unsigned int*)l, 16, 0, 0);
}

// fp32 -> bf16 cast of x + 5 weight matrices, one launch.
__global__ __launch_bounds__(256) void k_cast(
    const float* __restrict__ s0, u16* __restrict__ d0,
    const float* __restrict__ s1, u16* __restrict__ d1,
    const float* __restrict__ s2, u16* __restrict__ d2,
    const float* __restrict__ s3, u16* __restrict__ d3,
    const float* __restrict__ s4, u16* __restrict__ d4,
    const float* __restrict__ s5, u16* __restrict__ d5)
{
  int b = blockIdx.x;
  const float* s; u16* d;
  if (b < 4096)       { s = s0; d = d0; }
  else if (b < 8192)  { s = s1; d = d1; b -= 4096; }
  else if (b < 9216)  { s = s2; d = d2; b -= 8192; }
  else if (b < 10240) { s = s3; d = d3; b -= 9216; }
  else if (b < 14336) { s = s4; d = d4; b -= 10240; }
  else                { s = s5; d = d5; b -= 14336; }
  const int i = (b * 256 + threadIdx.x) * 4;
  const float4 v = *(const float4*)(s + i);
  ushort4 o;
  o.x = f2bf(v.x); o.y = f2bf(v.y); o.z = f2bf(v.z); o.w = f2bf(v.w);
  *(ushort4*)(d + i) = o;
}

// C[128 x 128] = A[128 x K] * B[128 x K]^T  (both K-contiguous bf16).
// Block 256 threads = 4 waves; wave w -> 64x64 quadrant; 16x16x32 MFMA; BK=32.
template <typename OT>
__device__ __forceinline__ void gemm_body(
    const u16* __restrict__ A, int lda,
    const u16* __restrict__ B, int ldb,
    OT* __restrict__ C, int ldc, int K,
    u16* As, u16* Bs)
{
  const int tid = threadIdx.x;
  const int wave = tid >> 6, lane = tid & 63;
  const int lrow = lane >> 2;            // 4 lanes per 32-elem row
  const int lcol = (lane & 3) * 8;
  const int wrow = (wave >> 1) * 64, wcol = (wave & 1) * 64;
  const int fr = lane & 15, fq = (lane >> 4) * 8;

  f32x4 acc[4][4];
  const f32x4 z = {0.f, 0.f, 0.f, 0.f};
  for (int i = 0; i < 4; i++) for (int j = 0; j < 4; j++) acc[i][j] = z;

  const u16* Ag = A + (size_t)(wave * 32 + lrow) * lda + lcol;
  const u16* Bg = B + (size_t)(wave * 32 + lrow) * ldb + lcol;
  u16* Asw = As + wave * 1024;
  u16* Bsw = Bs + wave * 1024;

  for (int k0 = 0; k0 < K; k0 += 32) {
    ld16(Ag + k0, Asw);
    ld16(Ag + k0 + (size_t)16 * lda, Asw + 512);
    ld16(Bg + k0, Bsw);
    ld16(Bg + k0 + (size_t)16 * ldb, Bsw + 512);
    __syncthreads();   // drains vmcnt (global_load_lds) before ds_read
    bf16x8 af[4], bfr[4];
    for (int i = 0; i < 4; i++) af[i]  = *(const bf16x8*)&As[(wrow + i * 16 + fr) * 32 + fq];
    for (int i = 0; i < 4; i++) bfr[i] = *(const bf16x8*)&Bs[(wcol + i * 16 + fr) * 32 + fq];
    for (int mi = 0; mi < 4; mi++)
      for (int ni = 0; ni < 4; ni++)
        acc[mi][ni] = __builtin_amdgcn_mfma_f32_16x16x32_bf16(af[mi], bfr[ni], acc[mi][ni], 0, 0, 0);
    __syncthreads();
  }
  const int er = (lane >> 4) * 4, ec = lane & 15;
  for (int mi = 0; mi < 4; mi++)
    for (int ni = 0; ni < 4; ni++)
      for (int r = 0; r < 4; r++) {
        const float v = acc[mi][ni][r];
        OT* p = C + (size_t)(wrow + mi * 16 + er + r) * ldc + wcol + ni * 16 + ec;
        if constexpr (sizeof(OT) == 2) *p = (OT)f2bf(v); else *p = (OT)v;
      }
}

// Fused QKVG projection: out[s][0:2048]=q, [2048:2560]=k, [2560:3072]=v, [3072:5120]=g
__global__ __launch_bounds__(256) void k_gemm_qkvg(
    const u16* __restrict__ x, const u16* __restrict__ wq, const u16* __restrict__ wk,
    const u16* __restrict__ wv, const u16* __restrict__ wg, u16* __restrict__ out)
{
  __shared__ __align__(16) u16 As[128 * 32];
  __shared__ __align__(16) u16 Bs[128 * 32];
  const int m0 = blockIdx.x * 128;
  const int c0 = blockIdx.y * 128;
  const u16* B; int br;
  if (c0 < 2048)      { B = wq; br = c0; }
  else if (c0 < 2560) { B = wk; br = c0 - 2048; }
  else if (c0 < 3072) { B = wv; br = c0 - 2560; }
  else                { B = wg; br = c0 - 3072; }
  gemm_body<u16>(x + (size_t)m0 * 2048, 2048, B + (size_t)br * 2048, 2048,
                 out + (size_t)m0 * 5120 + c0, 5120, 2048, As, Bs);
}

__global__ __launch_bounds__(256) void k_gemm_out(
    const u16* __restrict__ a, const u16* __restrict__ wo, float* __restrict__ out)
{
  __shared__ __align__(16) u16 As[128 * 32];
  __shared__ __align__(16) u16 Bs[128 * 32];
  const int m0 = blockIdx.x * 128;
  const int c0 = blockIdx.y * 128;
  gemm_body<float>(a + (size_t)m0 * 2048, 2048, wo + (size_t)c0 * 2048, 2048,
                   out + (size_t)m0 * 2048 + c0, 2048, 2048, As, Bs);
}

// RoPE + per-head RMSNorm, in-place on q and k regions of qkvg (bf16).
__global__ __launch_bounds__(256) void k_rope_norm(
    u16* __restrict__ qkvg, const float* __restrict__ cosp, const float* __restrict__ sinp,
    const float* __restrict__ qn, const float* __restrict__ kn)
{
  const int wid = (blockIdx.x * 256 + threadIdx.x) >> 6;
  const int lane = threadIdx.x & 63;
  const int s = wid / 40, h = wid - s * 40;
  u16* base; const float* wn;
  if (h < 32) { base = qkvg + (size_t)s * 5120 + h * 64;                wn = qn; }
  else        { base = qkvg + (size_t)s * 5120 + 2048 + (h - 32) * 64; wn = kn; }
  const int j = lane;
  float o0 = 0.f, o1 = 0.f;
  const bool act = lane < 32;
  if (act) {
    const unsigned int u = *(const unsigned int*)(base + 2 * j);
    const float xr = bf2f((u16)(u & 0xffffu)), xi = bf2f((u16)(u >> 16));
    const float c = cosp[s * 32 + j], sn = sinp[s * 32 + j];
    o0 = xr * c - xi * sn;
    o1 = xr * sn + xi * c;
  }
  float ss = o0 * o0 + o1 * o1;
  for (int m = 1; m <= 16; m <<= 1) ss += __shfl_xor(ss, m, 64);
  if (act) {
    const float inv = rsqrtf(ss * (1.0f / 64.0f) + 1e-6f);
    const u16 r0 = f2bf(o0 * inv * wn[2 * j]);
    const u16 r1 = f2bf(o1 * inv * wn[2 * j + 1]);
    *(unsigned int*)(base + 2 * j) = (unsigned int)r0 | ((unsigned int)r1 << 16);
  }
}

// v[s][g*64+d] -> vt[(g*64+d)][s]
__global__ __launch_bounds__(256) void k_vtrans(const u16* __restrict__ qkvg, u16* __restrict__ vt)
{
  const int idx = blockIdx.x * 256 + threadIdx.x;   // gd*2048 + s
  const int s = idx & 2047, gd = idx >> 11;
  vt[idx] = qkvg[(size_t)s * 5120 + 2560 + gd];
}

// ---- Split-KV flash attention pass 1: partial (O, m, l) per (q-tile, head, chunk).
// chunk c in [0,80) maps to (qt, ci); block processes KV tiles t = ci*8 .. min(ci*8+8, qt+1).
// 4 waves; wave w owns rows w*16..w*16+16 of the 64-row q-tile.
__global__ __launch_bounds__(256) void k_attn_part(
    const u16* __restrict__ qkvg, const u16* __restrict__ vt,
    u16* __restrict__ part, float* __restrict__ ml)
{
  __shared__ __align__(16) u16 Qs[64 * 64];
  __shared__ __align__(16) u16 Ks[64 * 64];
  __shared__ __align__(16) u16 Vs[64 * 64];   // V^T tile: [hd][key]
  __shared__ __align__(16) u16 Ps[64 * 72];   // padded: row stride 144 B kills 8-way conflicts
  const int c = blockIdx.x, h = blockIdx.y, g = h >> 2;
  int qt, ci;
  if (c < 8)       { qt = c;                 ci = 0; }
  else if (c < 24) { qt = 8 + ((c - 8) >> 1);  ci = (c - 8) & 1; }
  else if (c < 48) { qt = 16 + (c - 24) / 3;   ci = (c - 24) % 3; }
  else             { qt = 24 + ((c - 48) >> 2); ci = (c - 48) & 3; }
  const int t0 = ci * 8;
  const int t1 = min(t0 + 8, qt + 1);
  const int q0 = qt * 64;
  const int tid = threadIdx.x, wave = tid >> 6, lane = tid & 63;
  const int rr = lane >> 3, cc = (lane & 7) * 8;   // staging: 8 lanes per 64-elem row
  const int fr = lane & 15, fq = (lane >> 4) * 8;  // MFMA fragment addressing

  {
    const u16* Qg = qkvg + (size_t)(q0 + wave * 16 + rr) * 5120 + h * 64 + cc;
    ld16(Qg, Qs + wave * 1024);
    ld16(Qg + (size_t)8 * 5120, Qs + wave * 1024 + 512);
  }

  f32x4 o[4];
  const f32x4 z = {0.f, 0.f, 0.f, 0.f};
  for (int i = 0; i < 4; i++) o[i] = z;
  float mrow[4], lrow[4];
  for (int r = 0; r < 4; r++) { mrow[r] = -1e30f; lrow[r] = 0.f; }

  for (int t = t0; t < t1; ++t) {
    const u16* Kg = qkvg + (size_t)(t * 64 + wave * 16 + rr) * 5120 + 2048 + g * 64 + cc;
    ld16(Kg, Ks + wave * 1024);
    ld16(Kg + (size_t)8 * 5120, Ks + wave * 1024 + 512);
    const u16* Vg = vt + (size_t)(g * 64 + wave * 16 + rr) * 2048 + t * 64 + cc;
    ld16(Vg, Vs + wave * 1024);
    ld16(Vg + (size_t)8 * 2048, Vs + wave * 1024 + 512);
    __syncthreads();

    // S = Q K^T (rows wave*16..+16, 64 keys)
    f32x4 sc[4];
    for (int i = 0; i < 4; i++) sc[i] = z;
    for (int k0 = 0; k0 < 64; k0 += 32) {
      const bf16x8 aq = *(const bf16x8*)&Qs[(wave * 16 + fr) * 64 + k0 + fq];
      for (int ni = 0; ni < 4; ni++) {
        const bf16x8 bk = *(const bf16x8*)&Ks[(ni * 16 + fr) * 64 + k0 + fq];
        sc[ni] = __builtin_amdgcn_mfma_f32_16x16x32_bf16(aq, bk, sc[ni], 0, 0, 0);
      }
    }

    // online softmax; C/D layout: row=(lane>>4)*4+r, col=ni*16+(lane&15)
    const int rbase = q0 + wave * 16 + (lane >> 4) * 4;
    for (int r = 0; r < 4; r++) {
      float sv[4];
      float mx = -1e30f;
      for (int ni = 0; ni < 4; ni++) {
        float s = sc[ni][r] * 0.125f;
        const int kc = t * 64 + ni * 16 + (lane & 15);
        if (kc > rbase + r) s = -1e30f;    // causal mask
        sv[ni] = s;
        mx = fmaxf(mx, s);
      }
      for (int m = 1; m <= 8; m <<= 1) mx = fmaxf(mx, __shfl_xor(mx, m, 64));
      const float mnew = fmaxf(mrow[r], mx);
      const float alpha = __expf(mrow[r] - mnew);
      mrow[r] = mnew;
      float ps = 0.f;
      for (int ni = 0; ni < 4; ni++) {
        const float p = __expf(sv[ni] - mnew);
        ps += p;
        Ps[(size_t)(wave * 16 + (lane >> 4) * 4 + r) * 72 + ni * 16 + (lane & 15)] = f2bf(p);
      }
      for (int m = 1; m <= 8; m <<= 1) ps += __shfl_xor(ps, m, 64);
      lrow[r] = lrow[r] * alpha + ps;
      for (int ni = 0; ni < 4; ni++) o[ni][r] *= alpha;
    }
    __syncthreads();   // P visible before PV

    // O += P @ V
    for (int k0 = 0; k0 < 64; k0 += 32) {
      const bf16x8 ap = *(const bf16x8*)&Ps[(wave * 16 + fr) * 72 + k0 + fq];
      for (int ni = 0; ni < 4; ni++) {
        const bf16x8 bv = *(const bf16x8*)&Vs[(ni * 16 + fr) * 64 + k0 + fq];
        o[ni] = __builtin_amdgcn_mfma_f32_16x16x32_bf16(ap, bv, o[ni], 0, 0, 0);
      }
    }
    __syncthreads();   // Vs/Ps dead before next staging
  }

  // partial epilogue: unnormalized O (bf16) + per-row (m, l) fp32
  const int pbase = (h * 80 + c) * 4096;
  for (int r = 0; r < 4; r++) {
    const int rl = wave * 16 + (lane >> 4) * 4 + r;
    for (int ni = 0; ni < 4; ni++)
      part[pbase + rl * 64 + ni * 16 + (lane & 15)] = f2bf(o[ni][r]);
    if ((lane & 15) == 0) {
      ml[((h * 80 + c) * 64 + rl) * 2 + 0] = mrow[r];
      ml[((h * 80 + c) * 64 + rl) * 2 + 1] = lrow[r];
    }
  }
}

// ---- Split-KV pass 2: merge <=4 chunk partials per (qt, head), fuse sigmoid gating.
__global__ __launch_bounds__(256) void k_attn_comb(
    const u16* __restrict__ part, const float* __restrict__ ml,
    const u16* __restrict__ qkvg, u16* __restrict__ aout)
{
  const int qt = blockIdx.x, h = blockIdx.y;
  const int w = threadIdx.x >> 6, lane = threadIdx.x & 63;
  int cb, nch;
  if (qt < 8)       { cb = qt;               nch = 1; }
  else if (qt < 16) { cb = 8 + 2 * (qt - 8);  nch = 2; }
  else if (qt < 24) { cb = 24 + 3 * (qt - 16); nch = 3; }
  else              { cb = 48 + 4 * (qt - 24); nch = 4; }
  for (int r = 0; r < 16; r++) {
    const int rl = w * 16 + r;
    const int row = qt * 64 + rl;
    float m[4], l[4], M = -1e30f;
    for (int cc = 0; cc < nch; cc++) {
      m[cc] = ml[((h * 80 + cb + cc) * 64 + rl) * 2 + 0];
      l[cc] = ml[((h * 80 + cb + cc) * 64 + rl) * 2 + 1];
      M = fmaxf(M, m[cc]);
    }
    float L = 0.f, o = 0.f;
    for (int cc = 0; cc < nch; cc++) {
      const float wgt = __expf(m[cc] - M);
      L += l[cc] * wgt;
      o += wgt * bf2f(part[(h * 80 + cb + cc) * 4096 + rl * 64 + lane]);
    }
    const float gv = bf2f(qkvg[(size_t)row * 5120 + 3072 + h * 64 + lane]);
    const float sig = 1.0f / (1.0f + __expf(-gv));
    aout[(size_t)row * 2048 + h * 64 + lane] = f2bf(o / L * sig);
  }
}

extern "C" void kernel_launch(void* const* d_in, const int* in_sizes, int n_in,
                              void* d_out, int out_size, void* d_ws, size_t ws_size,
                              hipStream_t stream)
{
  const float* x  = (const float*)d_in[0];
  const float* cs = (const float*)d_in[1];
  const float* sn = (const float*)d_in[2];
  const float* wq = (const float*)d_in[3];
  const float* wk = (const float*)d_in[4];
  const float* wv = (const float*)d_in[5];
  const float* wo = (const float*)d_in[6];
  const float* wg = (const float*)d_in[7];
  const float* qn = (const float*)d_in[8];
  const float* kn = (const float*)d_in[9];
  float* out = (float*)d_out;

  // cast region first (xb..wgb contiguous 14M u16 = 28 MB; dead after qkvg gemm,
  // reused as attention partials), wob kept alive after it.
  u16* xb   = (u16*)d_ws;                      // 4M elems
  u16* wqb  = xb  + (size_t)4194304;           // 4M
  u16* wkb  = wqb + (size_t)4194304;           // 1M
  u16* wvb  = wkb + (size_t)1048576;           // 1M
  u16* wgb  = wvb + (size_t)1048576;           // 4M
  u16* wob  = wgb + (size_t)4194304;           // 4M  (alive until final gemm)
  u16* qkvg = wob + (size_t)4194304;           // 2048*5120
  u16* vt   = qkvg + (size_t)2048 * 5120;      // 512*2048
  u16* aws  = vt   + (size_t)512 * 2048;       // 2048*2048

  // attention partials overlay the dead cast region (needs 22.3 MB <= 28 MB)
  u16*   part = xb;                                  // 32*80*4096 bf16 = 21 MB
  float* ml   = (float*)(xb + (size_t)32 * 80 * 4096);  // 32*80*64*2 fp32 = 1.3 MB

  k_cast<<<dim3(18432), 256, 0, stream>>>(x, xb, wq, wqb, wk, wkb, wv, wvb, wo, wob, wg, wgb);
  k_gemm_qkvg<<<dim3(16, 40), 256, 0, stream>>>(xb, wqb, wkb, wvb, wgb, qkvg);
  k_rope_norm<<<dim3(2048 * 40 / 4), 256, 0, stream>>>(qkvg, cs, sn, qn, kn);
  k_vtrans<<<dim3(512 * 2048 / 256), 256, 0, stream>>>(qkvg, vt);
  k_attn_part<<<dim3(80, 32), 256, 0, stream>>>(qkvg, vt, part, ml);
  k_attn_comb<<<dim3(32, 32), 256, 0, stream>>>(part, ml, qkvg, aws);
  k_gemm_out<<<dim3(16, 16), 256, 0, stream>>>(aws, wob, out);
}

// Round 4
// 352.853 us; speedup vs baseline: 1.1141x; 1.0846x over previous
//
#include <hip/hip_runtime.h>
#include <stdint.h>

typedef unsigned short u16;
typedef __bf16 bf16x8 __attribute__((ext_vector_type(8)));
typedef float f32x4 __attribute__((ext_vector_type(4)));

__device__ __forceinline__ float bf2f(u16 u) {
  union { unsigned int i; float f; } v; v.i = ((unsigned int)u) << 16; return v.f;
}
__device__ __forceinline__ u16 f2bf(float f) {
  union { float f; unsigned int i; } v; v.f = f;
  unsigned int r = v.i + 0x7fffu + ((v.i >> 16) & 1u);
  return (u16)(r >> 16);
}
__device__ __forceinline__ u16 f2bf_trunc(float f) {   // cheap trunc for P-tile stores
  union { float f; unsigned int i; } v; v.f = f;
  return (u16)(v.i >> 16);
}
// async global->LDS, 16B per lane. LDS dest is wave-uniform base + lane*16.
__device__ __forceinline__ void ld16(const void* g, void* l) {
  __builtin_amdgcn_global_load_lds(
      (const __attribute__((address_space(1))) unsigned int*)g,
      (__attribute__((address_space(3))) unsigned int*)l, 16, 0, 0);
}

// fp32 -> bf16 cast of x + 5 weight matrices, one launch.
__global__ __launch_bounds__(256) void k_cast(
    const float* __restrict__ s0, u16* __restrict__ d0,
    const float* __restrict__ s1, u16* __restrict__ d1,
    const float* __restrict__ s2, u16* __restrict__ d2,
    const float* __restrict__ s3, u16* __restrict__ d3,
    const float* __restrict__ s4, u16* __restrict__ d4,
    const float* __restrict__ s5, u16* __restrict__ d5)
{
  int b = blockIdx.x;
  const float* s; u16* d;
  if (b < 4096)       { s = s0; d = d0; }
  else if (b < 8192)  { s = s1; d = d1; b -= 4096; }
  else if (b < 9216)  { s = s2; d = d2; b -= 8192; }
  else if (b < 10240) { s = s3; d = d3; b -= 9216; }
  else if (b < 14336) { s = s4; d = d4; b -= 10240; }
  else                { s = s5; d = d5; b -= 14336; }
  const int i = (b * 256 + threadIdx.x) * 4;
  const float4 v = *(const float4*)(s + i);
  ushort4 o;
  o.x = f2bf(v.x); o.y = f2bf(v.y); o.z = f2bf(v.z); o.w = f2bf(v.w);
  *(ushort4*)(d + i) = o;
}

// C[128 x 128] = A[128 x K] * B[128 x K]^T  (both K-contiguous bf16).
template <typename OT>
__device__ __forceinline__ void gemm_body(
    const u16* __restrict__ A, int lda,
    const u16* __restrict__ B, int ldb,
    OT* __restrict__ C, int ldc, int K,
    u16* As, u16* Bs)
{
  const int tid = threadIdx.x;
  const int wave = tid >> 6, lane = tid & 63;
  const int lrow = lane >> 2;
  const int lcol = (lane & 3) * 8;
  const int wrow = (wave >> 1) * 64, wcol = (wave & 1) * 64;
  const int fr = lane & 15, fq = (lane >> 4) * 8;

  f32x4 acc[4][4];
  const f32x4 z = {0.f, 0.f, 0.f, 0.f};
  for (int i = 0; i < 4; i++) for (int j = 0; j < 4; j++) acc[i][j] = z;

  const u16* Ag = A + (size_t)(wave * 32 + lrow) * lda + lcol;
  const u16* Bg = B + (size_t)(wave * 32 + lrow) * ldb + lcol;
  u16* Asw = As + wave * 1024;
  u16* Bsw = Bs + wave * 1024;

  for (int k0 = 0; k0 < K; k0 += 32) {
    ld16(Ag + k0, Asw);
    ld16(Ag + k0 + (size_t)16 * lda, Asw + 512);
    ld16(Bg + k0, Bsw);
    ld16(Bg + k0 + (size_t)16 * ldb, Bsw + 512);
    __syncthreads();
    bf16x8 af[4], bfr[4];
    for (int i = 0; i < 4; i++) af[i]  = *(const bf16x8*)&As[(wrow + i * 16 + fr) * 32 + fq];
    for (int i = 0; i < 4; i++) bfr[i] = *(const bf16x8*)&Bs[(wcol + i * 16 + fr) * 32 + fq];
    for (int mi = 0; mi < 4; mi++)
      for (int ni = 0; ni < 4; ni++)
        acc[mi][ni] = __builtin_amdgcn_mfma_f32_16x16x32_bf16(af[mi], bfr[ni], acc[mi][ni], 0, 0, 0);
    __syncthreads();
  }
  const int er = (lane >> 4) * 4, ec = lane & 15;
  for (int mi = 0; mi < 4; mi++)
    for (int ni = 0; ni < 4; ni++)
      for (int r = 0; r < 4; r++) {
        const float v = acc[mi][ni][r];
        OT* p = C + (size_t)(wrow + mi * 16 + er + r) * ldc + wcol + ni * 16 + ec;
        if constexpr (sizeof(OT) == 2) *p = (OT)f2bf(v); else *p = (OT)v;
      }
}

__global__ __launch_bounds__(256) void k_gemm_qkvg(
    const u16* __restrict__ x, const u16* __restrict__ wq, const u16* __restrict__ wk,
    const u16* __restrict__ wv, const u16* __restrict__ wg, u16* __restrict__ out)
{
  __shared__ __align__(16) u16 As[128 * 32];
  __shared__ __align__(16) u16 Bs[128 * 32];
  const int m0 = blockIdx.x * 128;
  const int c0 = blockIdx.y * 128;
  const u16* B; int br;
  if (c0 < 2048)      { B = wq; br = c0; }
  else if (c0 < 2560) { B = wk; br = c0 - 2048; }
  else if (c0 < 3072) { B = wv; br = c0 - 2560; }
  else                { B = wg; br = c0 - 3072; }
  gemm_body<u16>(x + (size_t)m0 * 2048, 2048, B + (size_t)br * 2048, 2048,
                 out + (size_t)m0 * 5120 + c0, 5120, 2048, As, Bs);
}

__global__ __launch_bounds__(256) void k_gemm_out(
    const u16* __restrict__ a, const u16* __restrict__ wo, float* __restrict__ out)
{
  __shared__ __align__(16) u16 As[128 * 32];
  __shared__ __align__(16) u16 Bs[128 * 32];
  const int m0 = blockIdx.x * 128;
  const int c0 = blockIdx.y * 128;
  gemm_body<float>(a + (size_t)m0 * 2048, 2048, wo + (size_t)c0 * 2048, 2048,
                   out + (size_t)m0 * 2048 + c0, 2048, 2048, As, Bs);
}

// RoPE + per-head RMSNorm, in-place on q and k regions of qkvg (bf16).
__global__ __launch_bounds__(256) void k_rope_norm(
    u16* __restrict__ qkvg, const float* __restrict__ cosp, const float* __restrict__ sinp,
    const float* __restrict__ qn, const float* __restrict__ kn)
{
  const int wid = (blockIdx.x * 256 + threadIdx.x) >> 6;
  const int lane = threadIdx.x & 63;
  const int s = wid / 40, h = wid - s * 40;
  u16* base; const float* wn;
  if (h < 32) { base = qkvg + (size_t)s * 5120 + h * 64;                wn = qn; }
  else        { base = qkvg + (size_t)s * 5120 + 2048 + (h - 32) * 64; wn = kn; }
  const int j = lane;
  float o0 = 0.f, o1 = 0.f;
  const bool act = lane < 32;
  if (act) {
    const unsigned int u = *(const unsigned int*)(base + 2 * j);
    const float xr = bf2f((u16)(u & 0xffffu)), xi = bf2f((u16)(u >> 16));
    const float c = cosp[s * 32 + j], sn = sinp[s * 32 + j];
    o0 = xr * c - xi * sn;
    o1 = xr * sn + xi * c;
  }
  float ss = o0 * o0 + o1 * o1;
  for (int m = 1; m <= 16; m <<= 1) ss += __shfl_xor(ss, m, 64);
  if (act) {
    const float inv = rsqrtf(ss * (1.0f / 64.0f) + 1e-6f);
    const u16 r0 = f2bf(o0 * inv * wn[2 * j]);
    const u16 r1 = f2bf(o1 * inv * wn[2 * j + 1]);
    *(unsigned int*)(base + 2 * j) = (unsigned int)r0 | ((unsigned int)r1 << 16);
  }
}

// LDS-tiled transpose: v[s][g*64+d] -> vt[(g*64+d)][s]. 64x64 tiles, both sides coalesced.
__global__ __launch_bounds__(256) void k_vtrans(const u16* __restrict__ qkvg, u16* __restrict__ vt)
{
  __shared__ u16 Ls[64 * 72];
  const int s0 = blockIdx.x * 64, g0 = blockIdx.y * 64;
  const int tid = threadIdx.x;
  const int lr = tid >> 4, lc = (tid & 15) * 4;   // 16 rows per pass, ushort4
  for (int p = 0; p < 4; p++) {
    const int r = p * 16 + lr;
    *(ushort4*)&Ls[r * 72 + lc] = *(const ushort4*)&qkvg[(size_t)(s0 + r) * 5120 + 2560 + g0 + lc];
  }
  __syncthreads();
  for (int p = 0; p < 4; p++) {
    const int r = p * 16 + lr;            // gd-row of output
    ushort4 o;
    o.x = Ls[(lc + 0) * 72 + r];
    o.y = Ls[(lc + 1) * 72 + r];
    o.z = Ls[(lc + 2) * 72 + r];
    o.w = Ls[(lc + 3) * 72 + r];
    *(ushort4*)&vt[(size_t)(g0 + r) * 2048 + s0 + lc] = o;
  }
}

// ---- Split-KV flash attention pass 1, fixed-max softmax (m=8 provable bound after RMSNorm).
// chunk c in [0,80) -> (qt, ci); block processes keys [ci*512, min(ci*512+512, (qt+1)*64)),
// in 128-key double-tiles (ghost keys are causally masked; K/V rows always in-bounds).
__global__ __launch_bounds__(256) void k_attn_part(
    const u16* __restrict__ qkvg, const u16* __restrict__ vt,
    u16* __restrict__ part, float* __restrict__ ml)
{
  __shared__ __align__(16) u16 Qs[64 * 64];    //  8 KB
  __shared__ __align__(16) u16 Ks[128 * 64];   // 16 KB  [key][hd]
  __shared__ __align__(16) u16 Vs[64 * 128];   // 16 KB  [hd][key]
  __shared__ __align__(16) u16 Ps[64 * 144];   // 18 KB  LD=144: 288B = 8 banks mod 32 -> conflict-free row groups
  const int c = blockIdx.x, h = blockIdx.y, g = h >> 2;
  int qt, ci;
  if (c < 8)       { qt = c;                 ci = 0; }
  else if (c < 24) { qt = 8 + ((c - 8) >> 1);  ci = (c - 8) & 1; }
  else if (c < 48) { qt = 16 + (c - 24) / 3;   ci = (c - 24) % 3; }
  else             { qt = 24 + ((c - 48) >> 2); ci = (c - 48) & 3; }
  const int kb0 = ci * 512;
  const int kend = min(kb0 + 512, (qt + 1) * 64);
  const int q0 = qt * 64;
  const int tid = threadIdx.x, wave = tid >> 6, lane = tid & 63;
  const int fr = lane & 15, fq = (lane >> 4) * 8;

  {
    const u16* Qg = qkvg + (size_t)(q0 + wave * 16 + (lane >> 3)) * 5120 + h * 64 + (lane & 7) * 8;
    ld16(Qg, Qs + wave * 1024);
    ld16(Qg + (size_t)8 * 5120, Qs + wave * 1024 + 512);
  }

  f32x4 o[4];
  const f32x4 z = {0.f, 0.f, 0.f, 0.f};
  for (int i = 0; i < 4; i++) o[i] = z;
  float lsum[4] = {0.f, 0.f, 0.f, 0.f};
  const int qrow = q0 + wave * 16 + (lane >> 4) * 4;   // +r

  for (int kb = kb0; kb < kend; kb += 128) {
    // stage K tile: 128 rows x 64 hd
    {
      const u16* Kg = qkvg + (size_t)(kb + wave * 8 + (lane >> 3)) * 5120 + 2048 + g * 64 + (lane & 7) * 8;
      for (int i = 0; i < 4; i++)
        ld16(Kg + (size_t)(i * 32) * 5120, Ks + (i * 32 + wave * 8) * 64);
    }
    // stage V^T tile: 64 hd x 128 keys
    {
      const u16* Vg = vt + (size_t)(g * 64 + wave * 4 + (lane >> 4)) * 2048 + kb + (lane & 15) * 8;
      for (int i = 0; i < 4; i++)
        ld16(Vg + (size_t)(i * 16) * 2048, Vs + (i * 16 + wave * 4) * 128);
    }
    __syncthreads();

    // S = Q K^T : 16 q-rows x 128 keys per wave
    f32x4 sc[8];
    for (int i = 0; i < 8; i++) sc[i] = z;
    const bf16x8 aq0 = *(const bf16x8*)&Qs[(wave * 16 + fr) * 64 + fq];
    const bf16x8 aq1 = *(const bf16x8*)&Qs[(wave * 16 + fr) * 64 + 32 + fq];
    for (int ni = 0; ni < 8; ni++) {
      const bf16x8 bk0 = *(const bf16x8*)&Ks[(ni * 16 + fr) * 64 + fq];
      const bf16x8 bk1 = *(const bf16x8*)&Ks[(ni * 16 + fr) * 64 + 32 + fq];
      sc[ni] = __builtin_amdgcn_mfma_f32_16x16x32_bf16(aq0, bk0, sc[ni], 0, 0, 0);
      sc[ni] = __builtin_amdgcn_mfma_f32_16x16x32_bf16(aq1, bk1, sc[ni], 0, 0, 0);
    }

    // fixed-max softmax: p = exp(s*0.125 - 8); masked -> 0. No cross-lane work.
    for (int r = 0; r < 4; r++) {
      float ls = 0.f;
      for (int ni = 0; ni < 8; ni++) {
        const int key = kb + ni * 16 + (lane & 15);
        float p = __expf(fmaf(sc[ni][r], 0.125f, -8.0f));
        p = (key <= qrow + r) ? p : 0.f;
        ls += p;
        Ps[(wave * 16 + (lane >> 4) * 4 + r) * 144 + ni * 16 + (lane & 15)] = f2bf_trunc(p);
      }
      lsum[r] += ls;
    }
    // Ps is same-wave produce/consume (rows wave*16..+16) -> no barrier needed.

    // O += P V : A from Ps, B from Vs
    for (int k0 = 0; k0 < 128; k0 += 32) {
      const bf16x8 ap = *(const bf16x8*)&Ps[(wave * 16 + fr) * 144 + k0 + fq];
      for (int ni = 0; ni < 4; ni++) {
        const bf16x8 bv = *(const bf16x8*)&Vs[(ni * 16 + fr) * 128 + k0 + fq];
        o[ni] = __builtin_amdgcn_mfma_f32_16x16x32_bf16(ap, bv, o[ni], 0, 0, 0);
      }
    }
    __syncthreads();   // Ks/Vs dead before next staging
  }

  // epilogue: reduce l across the 16-lane row group; store unnormalized O + l.
  const int pbase = (h * 80 + c) * 4096;
  for (int r = 0; r < 4; r++) {
    float L = lsum[r];
    for (int m = 1; m <= 8; m <<= 1) L += __shfl_xor(L, m, 64);
    const int rl = wave * 16 + (lane >> 4) * 4 + r;
    for (int ni = 0; ni < 4; ni++)
      part[pbase + rl * 64 + ni * 16 + (lane & 15)] = f2bf(o[ni][r]);
    if ((lane & 15) == 0) ml[(h * 80 + c) * 64 + rl] = L;
  }
}

// ---- Split-KV pass 2: fixed shared max -> plain sums; fuse sigmoid gating.
__global__ __launch_bounds__(256) void k_attn_comb(
    const u16* __restrict__ part, const float* __restrict__ ml,
    const u16* __restrict__ qkvg, u16* __restrict__ aout)
{
  const int qt = blockIdx.x, h = blockIdx.y;
  const int w = threadIdx.x >> 6, lane = threadIdx.x & 63;
  int cb, nch;
  if (qt < 8)       { cb = qt;               nch = 1; }
  else if (qt < 16) { cb = 8 + 2 * (qt - 8);  nch = 2; }
  else if (qt < 24) { cb = 24 + 3 * (qt - 16); nch = 3; }
  else              { cb = 48 + 4 * (qt - 24); nch = 4; }
  for (int r = 0; r < 16; r++) {
    const int rl = w * 16 + r;
    const int row = qt * 64 + rl;
    float L = 0.f, o = 0.f;
    for (int cc = 0; cc < nch; cc++) {
      L += ml[(h * 80 + cb + cc) * 64 + rl];
      o += bf2f(part[(h * 80 + cb + cc) * 4096 + rl * 64 + lane]);
    }
    const float gv = bf2f(qkvg[(size_t)row * 5120 + 3072 + h * 64 + lane]);
    const float sig = 1.0f / (1.0f + __expf(-gv));
    aout[(size_t)row * 2048 + h * 64 + lane] = f2bf(o / L * sig);
  }
}

extern "C" void kernel_launch(void* const* d_in, const int* in_sizes, int n_in,
                              void* d_out, int out_size, void* d_ws, size_t ws_size,
                              hipStream_t stream)
{
  const float* x  = (const float*)d_in[0];
  const float* cs = (const float*)d_in[1];
  const float* sn = (const float*)d_in[2];
  const float* wq = (const float*)d_in[3];
  const float* wk = (const float*)d_in[4];
  const float* wv = (const float*)d_in[5];
  const float* wo = (const float*)d_in[6];
  const float* wg = (const float*)d_in[7];
  const float* qn = (const float*)d_in[8];
  const float* kn = (const float*)d_in[9];
  float* out = (float*)d_out;

  u16* xb   = (u16*)d_ws;                      // 4M elems  (cast region, dead after qkvg gemm)
  u16* wqb  = xb  + (size_t)4194304;           // 4M
  u16* wkb  = wqb + (size_t)4194304;           // 1M
  u16* wvb  = wkb + (size_t)1048576;           // 1M
  u16* wgb  = wvb + (size_t)1048576;           // 4M
  u16* wob  = wgb + (size_t)4194304;           // 4M  (alive until final gemm)
  u16* qkvg = wob + (size_t)4194304;           // 2048*5120
  u16* vt   = qkvg + (size_t)2048 * 5120;      // 512*2048
  u16* aws  = vt   + (size_t)512 * 2048;       // 2048*2048

  // attention partials overlay the dead cast region (21.6 MB <= 28 MB)
  u16*   part = xb;                                     // 32*80*4096 bf16 = 21 MB
  float* ml   = (float*)(xb + (size_t)32 * 80 * 4096);  // 32*80*64 fp32 = 0.64 MB

  k_cast<<<dim3(18432), 256, 0, stream>>>(x, xb, wq, wqb, wk, wkb, wv, wvb, wo, wob, wg, wgb);
  k_gemm_qkvg<<<dim3(16, 40), 256, 0, stream>>>(xb, wqb, wkb, wvb, wgb, qkvg);
  k_rope_norm<<<dim3(2048 * 40 / 4), 256, 0, stream>>>(qkvg, cs, sn, qn, kn);
  k_vtrans<<<dim3(32, 8), 256, 0, stream>>>(qkvg, vt);
  k_attn_part<<<dim3(80, 32), 256, 0, stream>>>(qkvg, vt, part, ml);
  k_attn_comb<<<dim3(32, 32), 256, 0, stream>>>(part, ml, qkvg, aws);
  k_gemm_out<<<dim3(16, 16), 256, 0, stream>>>(aws, wob, out);
}

// Round 5
// 309.406 us; speedup vs baseline: 1.2705x; 1.1404x over previous
//
#include <hip/hip_runtime.h>
#include <stdint.h>

typedef unsigned short u16;
typedef __bf16 bf16x8 __attribute__((ext_vector_type(8)));
typedef float f32x4 __attribute__((ext_vector_type(4)));

__device__ __forceinline__ float bf2f(u16 u) {
  union { unsigned int i; float f; } v; v.i = ((unsigned int)u) << 16; return v.f;
}
__device__ __forceinline__ u16 f2bf(float f) {
  union { float f; unsigned int i; } v; v.f = f;
  unsigned int r = v.i + 0x7fffu + ((v.i >> 16) & 1u);
  return (u16)(r >> 16);
}
__device__ __forceinline__ u16 f2bf_trunc(float f) {   // cheap trunc for P-tile stores
  union { float f; unsigned int i; } v; v.f = f;
  return (u16)(v.i >> 16);
}
// async global->LDS, 16B per lane. LDS dest is wave-uniform base + lane*16.
__device__ __forceinline__ void ld16(const void* g, void* l) {
  __builtin_amdgcn_global_load_lds(
      (const __attribute__((address_space(1))) unsigned int*)g,
      (__attribute__((address_space(3))) unsigned int*)l, 16, 0, 0);
}

// fp32 -> bf16 cast of x + 5 weight matrices, one launch.
__global__ __launch_bounds__(256) void k_cast(
    const float* __restrict__ s0, u16* __restrict__ d0,
    const float* __restrict__ s1, u16* __restrict__ d1,
    const float* __restrict__ s2, u16* __restrict__ d2,
    const float* __restrict__ s3, u16* __restrict__ d3,
    const float* __restrict__ s4, u16* __restrict__ d4,
    const float* __restrict__ s5, u16* __restrict__ d5)
{
  int b = blockIdx.x;
  const float* s; u16* d;
  if (b < 4096)       { s = s0; d = d0; }
  else if (b < 8192)  { s = s1; d = d1; b -= 4096; }
  else if (b < 9216)  { s = s2; d = d2; b -= 8192; }
  else if (b < 10240) { s = s3; d = d3; b -= 9216; }
  else if (b < 14336) { s = s4; d = d4; b -= 10240; }
  else                { s = s5; d = d5; b -= 14336; }
  const int i = (b * 256 + threadIdx.x) * 4;
  const float4 v = *(const float4*)(s + i);
  ushort4 o;
  o.x = f2bf(v.x); o.y = f2bf(v.y); o.z = f2bf(v.z); o.w = f2bf(v.w);
  *(ushort4*)(d + i) = o;
}

// C[128 x 128] = A[128 x K] * B[128 x K]^T  (both K-contiguous bf16).
template <typename OT>
__device__ __forceinline__ void gemm_body(
    const u16* __restrict__ A, int lda,
    const u16* __restrict__ B, int ldb,
    OT* __restrict__ C, int ldc, int K,
    u16* As, u16* Bs)
{
  const int tid = threadIdx.x;
  const int wave = tid >> 6, lane = tid & 63;
  const int lrow = lane >> 2;
  const int lcol = (lane & 3) * 8;
  const int wrow = (wave >> 1) * 64, wcol = (wave & 1) * 64;
  const int fr = lane & 15, fq = (lane >> 4) * 8;

  f32x4 acc[4][4];
  const f32x4 z = {0.f, 0.f, 0.f, 0.f};
  for (int i = 0; i < 4; i++) for (int j = 0; j < 4; j++) acc[i][j] = z;

  const u16* Ag = A + (size_t)(wave * 32 + lrow) * lda + lcol;
  const u16* Bg = B + (size_t)(wave * 32 + lrow) * ldb + lcol;
  u16* Asw = As + wave * 1024;
  u16* Bsw = Bs + wave * 1024;

  for (int k0 = 0; k0 < K; k0 += 32) {
    ld16(Ag + k0, Asw);
    ld16(Ag + k0 + (size_t)16 * lda, Asw + 512);
    ld16(Bg + k0, Bsw);
    ld16(Bg + k0 + (size_t)16 * ldb, Bsw + 512);
    __syncthreads();
    bf16x8 af[4], bfr[4];
    for (int i = 0; i < 4; i++) af[i]  = *(const bf16x8*)&As[(wrow + i * 16 + fr) * 32 + fq];
    for (int i = 0; i < 4; i++) bfr[i] = *(const bf16x8*)&Bs[(wcol + i * 16 + fr) * 32 + fq];
    for (int mi = 0; mi < 4; mi++)
      for (int ni = 0; ni < 4; ni++)
        acc[mi][ni] = __builtin_amdgcn_mfma_f32_16x16x32_bf16(af[mi], bfr[ni], acc[mi][ni], 0, 0, 0);
    __syncthreads();
  }
  const int er = (lane >> 4) * 4, ec = lane & 15;
  for (int mi = 0; mi < 4; mi++)
    for (int ni = 0; ni < 4; ni++)
      for (int r = 0; r < 4; r++) {
        const float v = acc[mi][ni][r];
        OT* p = C + (size_t)(wrow + mi * 16 + er + r) * ldc + wcol + ni * 16 + ec;
        if constexpr (sizeof(OT) == 2) *p = (OT)f2bf(v); else *p = (OT)v;
      }
}

__global__ __launch_bounds__(256) void k_gemm_qkvg(
    const u16* __restrict__ x, const u16* __restrict__ wq, const u16* __restrict__ wk,
    const u16* __restrict__ wv, const u16* __restrict__ wg, u16* __restrict__ out)
{
  __shared__ __align__(16) u16 As[128 * 32];
  __shared__ __align__(16) u16 Bs[128 * 32];
  const int m0 = blockIdx.x * 128;
  const int c0 = blockIdx.y * 128;
  const u16* B; int br;
  if (c0 < 2048)      { B = wq; br = c0; }
  else if (c0 < 2560) { B = wk; br = c0 - 2048; }
  else if (c0 < 3072) { B = wv; br = c0 - 2560; }
  else                { B = wg; br = c0 - 3072; }
  gemm_body<u16>(x + (size_t)m0 * 2048, 2048, B + (size_t)br * 2048, 2048,
                 out + (size_t)m0 * 5120 + c0, 5120, 2048, As, Bs);
}

__global__ __launch_bounds__(256) void k_gemm_out(
    const u16* __restrict__ a, const u16* __restrict__ wo, float* __restrict__ out)
{
  __shared__ __align__(16) u16 As[128 * 32];
  __shared__ __align__(16) u16 Bs[128 * 32];
  const int m0 = blockIdx.x * 128;
  const int c0 = blockIdx.y * 128;
  gemm_body<float>(a + (size_t)m0 * 2048, 2048, wo + (size_t)c0 * 2048, 2048,
                   out + (size_t)m0 * 2048 + c0, 2048, 2048, As, Bs);
}

// RoPE + per-head RMSNorm, in-place on q and k regions of qkvg (bf16).
// One wave handles TWO heads: lanes 0-31 -> head 2hp, lanes 32-63 -> head 2hp+1.
__global__ __launch_bounds__(256) void k_rope_norm(
    u16* __restrict__ qkvg, const float* __restrict__ cosp, const float* __restrict__ sinp,
    const float* __restrict__ qn, const float* __restrict__ kn)
{
  const int wid = (blockIdx.x * 256 + threadIdx.x) >> 6;
  const int lane = threadIdx.x & 63;
  const int s = wid / 20, hp = wid - s * 20;
  const int h = hp * 2 + (lane >> 5);
  const int j = lane & 31;
  u16* base; const float* wn;
  if (h < 32) { base = qkvg + (size_t)s * 5120 + h * 64;                wn = qn; }
  else        { base = qkvg + (size_t)s * 5120 + 2048 + (h - 32) * 64; wn = kn; }
  const unsigned int u = *(const unsigned int*)(base + 2 * j);
  const float xr = bf2f((u16)(u & 0xffffu)), xi = bf2f((u16)(u >> 16));
  const float c = cosp[s * 32 + j], sn = sinp[s * 32 + j];
  const float o0 = xr * c - xi * sn;
  const float o1 = xr * sn + xi * c;
  float ss = o0 * o0 + o1 * o1;
  for (int m = 1; m <= 16; m <<= 1) ss += __shfl_xor(ss, m, 64);  // stays within 32-lane half
  const float inv = rsqrtf(ss * (1.0f / 64.0f) + 1e-6f);
  const u16 r0 = f2bf(o0 * inv * wn[2 * j]);
  const u16 r1 = f2bf(o1 * inv * wn[2 * j + 1]);
  *(unsigned int*)(base + 2 * j) = (unsigned int)r0 | ((unsigned int)r1 << 16);
}

// LDS-tiled transpose: v[s][g*64+d] -> vt[(g*64+d)][s]. 64x64 tiles, both sides coalesced.
__global__ __launch_bounds__(256) void k_vtrans(const u16* __restrict__ qkvg, u16* __restrict__ vt)
{
  __shared__ u16 Ls[64 * 72];
  const int s0 = blockIdx.x * 64, g0 = blockIdx.y * 64;
  const int tid = threadIdx.x;
  const int lr = tid >> 4, lc = (tid & 15) * 4;
  for (int p = 0; p < 4; p++) {
    const int r = p * 16 + lr;
    *(ushort4*)&Ls[r * 72 + lc] = *(const ushort4*)&qkvg[(size_t)(s0 + r) * 5120 + 2560 + g0 + lc];
  }
  __syncthreads();
  for (int p = 0; p < 4; p++) {
    const int r = p * 16 + lr;
    ushort4 o;
    o.x = Ls[(lc + 0) * 72 + r];
    o.y = Ls[(lc + 1) * 72 + r];
    o.z = Ls[(lc + 2) * 72 + r];
    o.w = Ls[(lc + 3) * 72 + r];
    *(ushort4*)&vt[(size_t)(g0 + r) * 2048 + s0 + lc] = o;
  }
}

// ---- Split-KV flash attention pass 1, fixed-max softmax (m=8 provable bound after RMSNorm).
// XOR-swizzled K/V LDS tiles (swizzle applied on the GLOBAL source address so the
// global_load_lds destination stays lane-contiguous): phys col-group = cg ^ (row&7).
// Q fragments live in registers (staged once through the Ks region).
__global__ __launch_bounds__(256) void k_attn_part(
    const u16* __restrict__ qkvg, const u16* __restrict__ vt,
    u16* __restrict__ part, float* __restrict__ ml)
{
  __shared__ __align__(16) u16 Ks[128 * 64];   // 16 KB  [key][hd], swizzled
  __shared__ __align__(16) u16 Vs[64 * 128];   // 16 KB  [hd][key], swizzled
  __shared__ __align__(16) u16 Ps[64 * 132];   // 16.5 KB  LD=132: 4-row stride = 264 words = 8 banks mod 32
  const int c = blockIdx.x, h = blockIdx.y, g = h >> 2;
  int qt, ci;
  if (c < 8)       { qt = c;                 ci = 0; }
  else if (c < 24) { qt = 8 + ((c - 8) >> 1);  ci = (c - 8) & 1; }
  else if (c < 48) { qt = 16 + (c - 24) / 3;   ci = (c - 24) % 3; }
  else             { qt = 24 + ((c - 48) >> 2); ci = (c - 48) & 3; }
  const int kb0 = ci * 512;
  const int kend = min(kb0 + 512, (qt + 1) * 64);
  const int q0 = qt * 64;
  const int tid = threadIdx.x, wave = tid >> 6, lane = tid & 63;
  const int fr = lane & 15, kg = lane >> 4, fq = kg * 8;
  const int sx = fr & 7;                        // reader swizzle key (row&7)

  // ---- stage Q (64x64, unswizzled) through Ks region, pull frags to registers.
  {
    const u16* Qg = qkvg + (size_t)(q0 + wave * 16 + (lane >> 3)) * 5120 + h * 64 + (lane & 7) * 8;
    ld16(Qg, Ks + wave * 1024);
    ld16(Qg + (size_t)8 * 5120, Ks + wave * 1024 + 512);
  }
  __syncthreads();
  const bf16x8 aq0 = *(const bf16x8*)&Ks[(wave * 16 + fr) * 64 + fq];
  const bf16x8 aq1 = *(const bf16x8*)&Ks[(wave * 16 + fr) * 64 + 32 + fq];
  __syncthreads();   // all waves done reading Q before K staging overwrites

  f32x4 o[4];
  const f32x4 z = {0.f, 0.f, 0.f, 0.f};
  for (int i = 0; i < 4; i++) o[i] = z;
  float lsum[4] = {0.f, 0.f, 0.f, 0.f};
  const int qrow = q0 + wave * 16 + kg * 4;   // +r

  // staging lane->row/colgroup decompositions (swizzle keys are i-invariant)
  const int krl = wave * 8 + (lane >> 3);             // K: 8 lanes per 64-u16 row
  const int kcg = (lane & 7) ^ (krl & 7);             // swizzled source col-group
  const int vrl = wave * 4 + kg;                      // V: 16 lanes per 128-u16 row
  const int vcg = fr ^ (vrl & 7);

  for (int kb = kb0; kb < kend; kb += 128) {
    {
      const u16* Kg = qkvg + (size_t)(kb + krl) * 5120 + 2048 + g * 64 + kcg * 8;
      for (int i = 0; i < 4; i++)
        ld16(Kg + (size_t)(i * 32) * 5120, Ks + (i * 32 + wave * 8) * 64);
    }
    {
      const u16* Vg = vt + (size_t)(g * 64 + vrl) * 2048 + kb + vcg * 8;
      for (int i = 0; i < 4; i++)
        ld16(Vg + (size_t)(i * 16) * 2048, Vs + (i * 16 + wave * 4) * 128);
    }
    __syncthreads();

    // S = Q K^T : 16 q-rows x 128 keys per wave (swizzled B reads: 2 lanes/bank)
    f32x4 sc[8];
    for (int i = 0; i < 8; i++) sc[i] = z;
    for (int ni = 0; ni < 8; ni++) {
      const bf16x8 bk0 = *(const bf16x8*)&Ks[(ni * 16 + fr) * 64 + (kg ^ sx) * 8];
      const bf16x8 bk1 = *(const bf16x8*)&Ks[(ni * 16 + fr) * 64 + ((kg + 4) ^ sx) * 8];
      sc[ni] = __builtin_amdgcn_mfma_f32_16x16x32_bf16(aq0, bk0, sc[ni], 0, 0, 0);
      sc[ni] = __builtin_amdgcn_mfma_f32_16x16x32_bf16(aq1, bk1, sc[ni], 0, 0, 0);
    }

    // fixed-max softmax: p = exp(s*0.125 - 8); masked -> 0. No cross-lane work.
    for (int r = 0; r < 4; r++) {
      float ls = 0.f;
      for (int ni = 0; ni < 8; ni++) {
        const int key = kb + ni * 16 + fr;
        float p = __expf(fmaf(sc[ni][r], 0.125f, -8.0f));
        p = (key <= qrow + r) ? p : 0.f;
        ls += p;
        Ps[(wave * 16 + kg * 4 + r) * 132 + ni * 16 + fr] = f2bf_trunc(p);
      }
      lsum[r] += ls;
    }
    // Ps is same-wave produce/consume (rows wave*16..+16) -> no barrier needed.

    // O += P V : A from Ps, B from swizzled Vs
    for (int k0 = 0; k0 < 128; k0 += 32) {
      const bf16x8 ap = *(const bf16x8*)&Ps[(wave * 16 + fr) * 132 + k0 + fq];
      for (int ni = 0; ni < 4; ni++) {
        const bf16x8 bv = *(const bf16x8*)&Vs[(ni * 16 + fr) * 128 + (((k0 >> 3) + kg) ^ sx) * 8];
        o[ni] = __builtin_amdgcn_mfma_f32_16x16x32_bf16(ap, bv, o[ni], 0, 0, 0);
      }
    }
    __syncthreads();   // Ks/Vs dead before next staging
  }

  // epilogue: reduce l across the 16-lane row group; store unnormalized O + l.
  const int pbase = (h * 80 + c) * 4096;
  for (int r = 0; r < 4; r++) {
    float L = lsum[r];
    for (int m = 1; m <= 8; m <<= 1) L += __shfl_xor(L, m, 64);
    const int rl = wave * 16 + kg * 4 + r;
    for (int ni = 0; ni < 4; ni++)
      part[pbase + rl * 64 + ni * 16 + fr] = f2bf(o[ni][r]);
    if (fr == 0) ml[(h * 80 + c) * 64 + rl] = L;
  }
}

// ---- Split-KV pass 2: fixed shared max -> plain sums; fuse sigmoid gating.
__global__ __launch_bounds__(256) void k_attn_comb(
    const u16* __restrict__ part, const float* __restrict__ ml,
    const u16* __restrict__ qkvg, u16* __restrict__ aout)
{
  const int qt = blockIdx.x, h = blockIdx.y;
  const int w = threadIdx.x >> 6, lane = threadIdx.x & 63;
  int cb, nch;
  if (qt < 8)       { cb = qt;               nch = 1; }
  else if (qt < 16) { cb = 8 + 2 * (qt - 8);  nch = 2; }
  else if (qt < 24) { cb = 24 + 3 * (qt - 16); nch = 3; }
  else              { cb = 48 + 4 * (qt - 24); nch = 4; }
  for (int r = 0; r < 16; r++) {
    const int rl = w * 16 + r;
    const int row = qt * 64 + rl;
    float L = 0.f, o = 0.f;
    for (int cc = 0; cc < nch; cc++) {
      L += ml[(h * 80 + cb + cc) * 64 + rl];
      o += bf2f(part[(h * 80 + cb + cc) * 4096 + rl * 64 + lane]);
    }
    const float gv = bf2f(qkvg[(size_t)row * 5120 + 3072 + h * 64 + lane]);
    const float sig = 1.0f / (1.0f + __expf(-gv));
    aout[(size_t)row * 2048 + h * 64 + lane] = f2bf(o / L * sig);
  }
}

extern "C" void kernel_launch(void* const* d_in, const int* in_sizes, int n_in,
                              void* d_out, int out_size, void* d_ws, size_t ws_size,
                              hipStream_t stream)
{
  const float* x  = (const float*)d_in[0];
  const float* cs = (const float*)d_in[1];
  const float* sn = (const float*)d_in[2];
  const float* wq = (const float*)d_in[3];
  const float* wk = (const float*)d_in[4];
  const float* wv = (const float*)d_in[5];
  const float* wo = (const float*)d_in[6];
  const float* wg = (const float*)d_in[7];
  const float* qn = (const float*)d_in[8];
  const float* kn = (const float*)d_in[9];
  float* out = (float*)d_out;

  u16* xb   = (u16*)d_ws;                      // 4M elems  (cast region, dead after qkvg gemm)
  u16* wqb  = xb  + (size_t)4194304;           // 4M
  u16* wkb  = wqb + (size_t)4194304;           // 1M
  u16* wvb  = wkb + (size_t)1048576;           // 1M
  u16* wgb  = wvb + (size_t)1048576;           // 4M
  u16* wob  = wgb + (size_t)4194304;           // 4M  (alive until final gemm)
  u16* qkvg = wob + (size_t)4194304;           // 2048*5120
  u16* vt   = qkvg + (size_t)2048 * 5120;      // 512*2048
  u16* aws  = vt   + (size_t)512 * 2048;       // 2048*2048

  // attention partials overlay the dead cast region (21.6 MB <= 28 MB)
  u16*   part = xb;                                     // 32*80*4096 bf16 = 21 MB
  float* ml   = (float*)(xb + (size_t)32 * 80 * 4096);  // 32*80*64 fp32 = 0.64 MB

  k_cast<<<dim3(18432), 256, 0, stream>>>(x, xb, wq, wqb, wk, wkb, wv, wvb, wo, wob, wg, wgb);
  k_gemm_qkvg<<<dim3(16, 40), 256, 0, stream>>>(xb, wqb, wkb, wvb, wgb, qkvg);
  k_rope_norm<<<dim3(2048 * 20 / 4), 256, 0, stream>>>(qkvg, cs, sn, qn, kn);
  k_vtrans<<<dim3(32, 8), 256, 0, stream>>>(qkvg, vt);
  k_attn_part<<<dim3(80, 32), 256, 0, stream>>>(qkvg, vt, part, ml);
  k_attn_comb<<<dim3(32, 32), 256, 0, stream>>>(part, ml, qkvg, aws);
  k_gemm_out<<<dim3(16, 16), 256, 0, stream>>>(aws, wob, out);
}

// Round 6
// 295.359 us; speedup vs baseline: 1.3309x; 1.0476x over previous
//
#include <hip/hip_runtime.h>
#include <stdint.h>

typedef unsigned short u16;
typedef __bf16 bf16x8 __attribute__((ext_vector_type(8)));
typedef float f32x4 __attribute__((ext_vector_type(4)));

__device__ __forceinline__ float bf2f(u16 u) {
  union { unsigned int i; float f; } v; v.i = ((unsigned int)u) << 16; return v.f;
}
__device__ __forceinline__ u16 f2bf(float f) {
  union { float f; unsigned int i; } v; v.f = f;
  unsigned int r = v.i + 0x7fffu + ((v.i >> 16) & 1u);
  return (u16)(r >> 16);
}
__device__ __forceinline__ u16 f2bf_trunc(float f) {   // cheap trunc for P-tile stores
  union { float f; unsigned int i; } v; v.f = f;
  return (u16)(v.i >> 16);
}
// async global->LDS, 16B per lane. LDS dest is wave-uniform base + lane*16.
__device__ __forceinline__ void ld16(const void* g, void* l) {
  __builtin_amdgcn_global_load_lds(
      (const __attribute__((address_space(1))) unsigned int*)g,
      (__attribute__((address_space(3))) unsigned int*)l, 16, 0, 0);
}

// fp32 -> bf16 cast of x + 5 weight matrices, one launch.
__global__ __launch_bounds__(256) void k_cast(
    const float* __restrict__ s0, u16* __restrict__ d0,
    const float* __restrict__ s1, u16* __restrict__ d1,
    const float* __restrict__ s2, u16* __restrict__ d2,
    const float* __restrict__ s3, u16* __restrict__ d3,
    const float* __restrict__ s4, u16* __restrict__ d4,
    const float* __restrict__ s5, u16* __restrict__ d5)
{
  int b = blockIdx.x;
  const float* s; u16* d;
  if (b < 4096)       { s = s0; d = d0; }
  else if (b < 8192)  { s = s1; d = d1; b -= 4096; }
  else if (b < 9216)  { s = s2; d = d2; b -= 8192; }
  else if (b < 10240) { s = s3; d = d3; b -= 9216; }
  else if (b < 14336) { s = s4; d = d4; b -= 10240; }
  else                { s = s5; d = d5; b -= 14336; }
  const int i = (b * 256 + threadIdx.x) * 4;
  const float4 v = *(const float4*)(s + i);
  ushort4 o;
  o.x = f2bf(v.x); o.y = f2bf(v.y); o.z = f2bf(v.z); o.w = f2bf(v.w);
  *(ushort4*)(d + i) = o;
}

// C[128 x 128] = A[128 x K] * B[128 x K]^T  (both K-contiguous bf16). BK=64,
// XOR-swizzled LDS (phys colgroup = cg ^ (row&7), applied on the GLOBAL source
// so global_load_lds destinations stay lane-contiguous). Row stride 64 u16 = 32
// words = 0 mod 32 banks; swizzle spreads each 16-lane read phase over all banks.
template <typename OT>
__device__ __forceinline__ void gemm_body(
    const u16* __restrict__ A, int lda,
    const u16* __restrict__ B, int ldb,
    OT* __restrict__ C, int ldc, int K,
    u16* As, u16* Bs)
{
  const int tid = threadIdx.x;
  const int wave = tid >> 6, lane = tid & 63;
  const int wrow = (wave >> 1) * 64, wcol = (wave & 1) * 64;
  const int fr = lane & 15, kg = lane >> 4;
  const int srl = lane >> 3;                 // staging row within an 8-row group
  const int scg = (lane & 7) ^ srl;          // swizzled source colgroup

  f32x4 acc[4][4];
  const f32x4 z = {0.f, 0.f, 0.f, 0.f};
  for (int i = 0; i < 4; i++) for (int j = 0; j < 4; j++) acc[i][j] = z;

  const u16* Ag = A + (size_t)(wave * 8 + srl) * lda + scg * 8;
  const u16* Bg = B + (size_t)(wave * 8 + srl) * ldb + scg * 8;
  u16* Asw = As + wave * 8 * 64;
  u16* Bsw = Bs + wave * 8 * 64;
  const int sxr = fr & 7;                    // reader swizzle key

  for (int k0 = 0; k0 < K; k0 += 64) {
    for (int i = 0; i < 4; i++) {
      ld16(Ag + k0 + (size_t)(i * 32) * lda, Asw + i * 32 * 64);
      ld16(Bg + k0 + (size_t)(i * 32) * ldb, Bsw + i * 32 * 64);
    }
    __syncthreads();
    bf16x8 af[4][2], bfr[4][2];
    for (int i = 0; i < 4; i++)
      for (int h = 0; h < 2; h++) {
        af[i][h]  = *(const bf16x8*)&As[(wrow + i * 16 + fr) * 64 + (((h * 4 + kg) ^ sxr)) * 8];
        bfr[i][h] = *(const bf16x8*)&Bs[(wcol + i * 16 + fr) * 64 + (((h * 4 + kg) ^ sxr)) * 8];
      }
    for (int h = 0; h < 2; h++)
      for (int mi = 0; mi < 4; mi++)
        for (int ni = 0; ni < 4; ni++)
          acc[mi][ni] = __builtin_amdgcn_mfma_f32_16x16x32_bf16(af[mi][h], bfr[ni][h], acc[mi][ni], 0, 0, 0);
    __syncthreads();
  }
  const int er = kg * 4, ec = fr;
  for (int mi = 0; mi < 4; mi++)
    for (int ni = 0; ni < 4; ni++)
      for (int r = 0; r < 4; r++) {
        const float v = acc[mi][ni][r];
        OT* p = C + (size_t)(wrow + mi * 16 + er + r) * ldc + wcol + ni * 16 + ec;
        if constexpr (sizeof(OT) == 2) *p = (OT)f2bf(v); else *p = (OT)v;
      }
}

__global__ __launch_bounds__(256) void k_gemm_qkvg(
    const u16* __restrict__ x, const u16* __restrict__ wq, const u16* __restrict__ wk,
    const u16* __restrict__ wv, const u16* __restrict__ wg, u16* __restrict__ out)
{
  __shared__ __align__(16) u16 As[128 * 64];
  __shared__ __align__(16) u16 Bs[128 * 64];
  const int m0 = blockIdx.x * 128;
  const int c0 = blockIdx.y * 128;
  const u16* B; int br;
  if (c0 < 2048)      { B = wq; br = c0; }
  else if (c0 < 2560) { B = wk; br = c0 - 2048; }
  else if (c0 < 3072) { B = wv; br = c0 - 2560; }
  else                { B = wg; br = c0 - 3072; }
  gemm_body<u16>(x + (size_t)m0 * 2048, 2048, B + (size_t)br * 2048, 2048,
                 out + (size_t)m0 * 5120 + c0, 5120, 2048, As, Bs);
}

__global__ __launch_bounds__(256) void k_gemm_out(
    const u16* __restrict__ a, const u16* __restrict__ wo, float* __restrict__ out)
{
  __shared__ __align__(16) u16 As[128 * 64];
  __shared__ __align__(16) u16 Bs[128 * 64];
  const int m0 = blockIdx.x * 128;
  const int c0 = blockIdx.y * 128;
  gemm_body<float>(a + (size_t)m0 * 2048, 2048, wo + (size_t)c0 * 2048, 2048,
                   out + (size_t)m0 * 2048 + c0, 2048, 2048, As, Bs);
}

// Merged prep: RoPE+RMSNorm (blocks [0,10240)) and V-transpose (blocks [10240,10496)).
// The two roles touch disjoint regions of qkvg (q/k vs v) -> safe in one dispatch.
__global__ __launch_bounds__(256) void k_prep(
    u16* __restrict__ qkvg, const float* __restrict__ cosp, const float* __restrict__ sinp,
    const float* __restrict__ qn, const float* __restrict__ kn, u16* __restrict__ vt)
{
  __shared__ u16 Ls[64 * 72];
  if (blockIdx.x < 10240) {
    // RoPE + per-head RMSNorm; one wave handles TWO heads (32 lanes each).
    const int wid = (blockIdx.x * 256 + threadIdx.x) >> 6;
    const int lane = threadIdx.x & 63;
    const int s = wid / 20, hp = wid - s * 20;
    const int h = hp * 2 + (lane >> 5);
    const int j = lane & 31;
    u16* base; const float* wn;
    if (h < 32) { base = qkvg + (size_t)s * 5120 + h * 64;                wn = qn; }
    else        { base = qkvg + (size_t)s * 5120 + 2048 + (h - 32) * 64; wn = kn; }
    const unsigned int u = *(const unsigned int*)(base + 2 * j);
    const float xr = bf2f((u16)(u & 0xffffu)), xi = bf2f((u16)(u >> 16));
    const float c = cosp[s * 32 + j], sn = sinp[s * 32 + j];
    const float o0 = xr * c - xi * sn;
    const float o1 = xr * sn + xi * c;
    float ss = o0 * o0 + o1 * o1;
    for (int m = 1; m <= 16; m <<= 1) ss += __shfl_xor(ss, m, 64);  // stays within 32-lane half
    const float inv = rsqrtf(ss * (1.0f / 64.0f) + 1e-6f);
    const u16 r0 = f2bf(o0 * inv * wn[2 * j]);
    const u16 r1 = f2bf(o1 * inv * wn[2 * j + 1]);
    *(unsigned int*)(base + 2 * j) = (unsigned int)r0 | ((unsigned int)r1 << 16);
  } else {
    // LDS-tiled transpose: v[s][g*64+d] -> vt[(g*64+d)][s].
    const int bb = blockIdx.x - 10240;
    const int s0 = (bb & 31) * 64, g0 = (bb >> 5) * 64;
    const int tid = threadIdx.x;
    const int lr = tid >> 4, lc = (tid & 15) * 4;
    for (int p = 0; p < 4; p++) {
      const int r = p * 16 + lr;
      *(ushort4*)&Ls[r * 72 + lc] = *(const ushort4*)&qkvg[(size_t)(s0 + r) * 5120 + 2560 + g0 + lc];
    }
    __syncthreads();
    for (int p = 0; p < 4; p++) {
      const int r = p * 16 + lr;
      ushort4 o;
      o.x = Ls[(lc + 0) * 72 + r];
      o.y = Ls[(lc + 1) * 72 + r];
      o.z = Ls[(lc + 2) * 72 + r];
      o.w = Ls[(lc + 3) * 72 + r];
      *(ushort4*)&vt[(size_t)(g0 + r) * 2048 + s0 + lc] = o;
    }
  }
}

// ---- Split-KV flash attention pass 1, fixed-max softmax (m=8 provable bound after RMSNorm).
__global__ __launch_bounds__(256) void k_attn_part(
    const u16* __restrict__ qkvg, const u16* __restrict__ vt,
    u16* __restrict__ part, float* __restrict__ ml)
{
  __shared__ __align__(16) u16 Ks[128 * 64];   // 16 KB  [key][hd], swizzled
  __shared__ __align__(16) u16 Vs[64 * 128];   // 16 KB  [hd][key], swizzled
  __shared__ __align__(16) u16 Ps[64 * 132];   // 16.5 KB  LD=132: 4-row stride = 264 words = 8 banks mod 32
  const int c = blockIdx.x, h = blockIdx.y, g = h >> 2;
  int qt, ci;
  if (c < 8)       { qt = c;                 ci = 0; }
  else if (c < 24) { qt = 8 + ((c - 8) >> 1);  ci = (c - 8) & 1; }
  else if (c < 48) { qt = 16 + (c - 24) / 3;   ci = (c - 24) % 3; }
  else             { qt = 24 + ((c - 48) >> 2); ci = (c - 48) & 3; }
  const int kb0 = ci * 512;
  const int kend = min(kb0 + 512, (qt + 1) * 64);
  const int q0 = qt * 64;
  const int tid = threadIdx.x, wave = tid >> 6, lane = tid & 63;
  const int fr = lane & 15, kg = lane >> 4, fq = kg * 8;
  const int sx = fr & 7;

  // stage Q (64x64, unswizzled) through Ks region, pull frags to registers.
  {
    const u16* Qg = qkvg + (size_t)(q0 + wave * 16 + (lane >> 3)) * 5120 + h * 64 + (lane & 7) * 8;
    ld16(Qg, Ks + wave * 1024);
    ld16(Qg + (size_t)8 * 5120, Ks + wave * 1024 + 512);
  }
  __syncthreads();
  const bf16x8 aq0 = *(const bf16x8*)&Ks[(wave * 16 + fr) * 64 + fq];
  const bf16x8 aq1 = *(const bf16x8*)&Ks[(wave * 16 + fr) * 64 + 32 + fq];
  __syncthreads();

  f32x4 o[4];
  const f32x4 z = {0.f, 0.f, 0.f, 0.f};
  for (int i = 0; i < 4; i++) o[i] = z;
  float lsum[4] = {0.f, 0.f, 0.f, 0.f};
  const int qrow = q0 + wave * 16 + kg * 4;

  const int krl = wave * 8 + (lane >> 3);
  const int kcg = (lane & 7) ^ (krl & 7);
  const int vrl = wave * 4 + kg;
  const int vcg = fr ^ (vrl & 7);

  for (int kb = kb0; kb < kend; kb += 128) {
    {
      const u16* Kg = qkvg + (size_t)(kb + krl) * 5120 + 2048 + g * 64 + kcg * 8;
      for (int i = 0; i < 4; i++)
        ld16(Kg + (size_t)(i * 32) * 5120, Ks + (i * 32 + wave * 8) * 64);
    }
    {
      const u16* Vg = vt + (size_t)(g * 64 + vrl) * 2048 + kb + vcg * 8;
      for (int i = 0; i < 4; i++)
        ld16(Vg + (size_t)(i * 16) * 2048, Vs + (i * 16 + wave * 4) * 128);
    }
    __syncthreads();

    f32x4 sc[8];
    for (int i = 0; i < 8; i++) sc[i] = z;
    for (int ni = 0; ni < 8; ni++) {
      const bf16x8 bk0 = *(const bf16x8*)&Ks[(ni * 16 + fr) * 64 + (kg ^ sx) * 8];
      const bf16x8 bk1 = *(const bf16x8*)&Ks[(ni * 16 + fr) * 64 + ((kg + 4) ^ sx) * 8];
      sc[ni] = __builtin_amdgcn_mfma_f32_16x16x32_bf16(aq0, bk0, sc[ni], 0, 0, 0);
      sc[ni] = __builtin_amdgcn_mfma_f32_16x16x32_bf16(aq1, bk1, sc[ni], 0, 0, 0);
    }

    for (int r = 0; r < 4; r++) {
      float ls = 0.f;
      for (int ni = 0; ni < 8; ni++) {
        const int key = kb + ni * 16 + fr;
        float p = __expf(fmaf(sc[ni][r], 0.125f, -8.0f));
        p = (key <= qrow + r) ? p : 0.f;
        ls += p;
        Ps[(wave * 16 + kg * 4 + r) * 132 + ni * 16 + fr] = f2bf_trunc(p);
      }
      lsum[r] += ls;
    }

    for (int k0 = 0; k0 < 128; k0 += 32) {
      const bf16x8 ap = *(const bf16x8*)&Ps[(wave * 16 + fr) * 132 + k0 + fq];
      for (int ni = 0; ni < 4; ni++) {
        const bf16x8 bv = *(const bf16x8*)&Vs[(ni * 16 + fr) * 128 + (((k0 >> 3) + kg) ^ sx) * 8];
        o[ni] = __builtin_amdgcn_mfma_f32_16x16x32_bf16(ap, bv, o[ni], 0, 0, 0);
      }
    }
    __syncthreads();
  }

  const int pbase = (h * 80 + c) * 4096;
  for (int r = 0; r < 4; r++) {
    float L = lsum[r];
    for (int m = 1; m <= 8; m <<= 1) L += __shfl_xor(L, m, 64);
    const int rl = wave * 16 + kg * 4 + r;
    for (int ni = 0; ni < 4; ni++)
      part[pbase + rl * 64 + ni * 16 + fr] = f2bf(o[ni][r]);
    if (fr == 0) ml[(h * 80 + c) * 64 + rl] = L;
  }
}

// ---- Split-KV pass 2: plain sums (shared fixed max); fuse sigmoid gating.
__global__ __launch_bounds__(256) void k_attn_comb(
    const u16* __restrict__ part, const float* __restrict__ ml,
    const u16* __restrict__ qkvg, u16* __restrict__ aout)
{
  const int qt = blockIdx.x, h = blockIdx.y;
  const int w = threadIdx.x >> 6, lane = threadIdx.x & 63;
  int cb, nch;
  if (qt < 8)       { cb = qt;               nch = 1; }
  else if (qt < 16) { cb = 8 + 2 * (qt - 8);  nch = 2; }
  else if (qt < 24) { cb = 24 + 3 * (qt - 16); nch = 3; }
  else              { cb = 48 + 4 * (qt - 24); nch = 4; }
  for (int r = 0; r < 16; r++) {
    const int rl = w * 16 + r;
    const int row = qt * 64 + rl;
    float L = 0.f, o = 0.f;
    for (int cc = 0; cc < nch; cc++) {
      L += ml[(h * 80 + cb + cc) * 64 + rl];
      o += bf2f(part[(h * 80 + cb + cc) * 4096 + rl * 64 + lane]);
    }
    const float gv = bf2f(qkvg[(size_t)row * 5120 + 3072 + h * 64 + lane]);
    const float sig = 1.0f / (1.0f + __expf(-gv));
    aout[(size_t)row * 2048 + h * 64 + lane] = f2bf(o / L * sig);
  }
}

extern "C" void kernel_launch(void* const* d_in, const int* in_sizes, int n_in,
                              void* d_out, int out_size, void* d_ws, size_t ws_size,
                              hipStream_t stream)
{
  const float* x  = (const float*)d_in[0];
  const float* cs = (const float*)d_in[1];
  const float* sn = (const float*)d_in[2];
  const float* wq = (const float*)d_in[3];
  const float* wk = (const float*)d_in[4];
  const float* wv = (const float*)d_in[5];
  const float* wo = (const float*)d_in[6];
  const float* wg = (const float*)d_in[7];
  const float* qn = (const float*)d_in[8];
  const float* kn = (const float*)d_in[9];
  float* out = (float*)d_out;

  u16* xb   = (u16*)d_ws;                      // 4M elems  (cast region, dead after qkvg gemm)
  u16* wqb  = xb  + (size_t)4194304;           // 4M
  u16* wkb  = wqb + (size_t)4194304;           // 1M
  u16* wvb  = wkb + (size_t)1048576;           // 1M
  u16* wgb  = wvb + (size_t)1048576;           // 4M
  u16* wob  = wgb + (size_t)4194304;           // 4M  (alive until final gemm)
  u16* qkvg = wob + (size_t)4194304;           // 2048*5120
  u16* vt   = qkvg + (size_t)2048 * 5120;      // 512*2048
  u16* aws  = vt   + (size_t)512 * 2048;       // 2048*2048

  u16*   part = xb;                                     // 32*80*4096 bf16 = 21 MB
  float* ml   = (float*)(xb + (size_t)32 * 80 * 4096);  // 32*80*64 fp32 = 0.64 MB

  k_cast<<<dim3(18432), 256, 0, stream>>>(x, xb, wq, wqb, wk, wkb, wv, wvb, wo, wob, wg, wgb);
  k_gemm_qkvg<<<dim3(16, 40), 256, 0, stream>>>(xb, wqb, wkb, wvb, wgb, qkvg);
  k_prep<<<dim3(10240 + 256), 256, 0, stream>>>(qkvg, cs, sn, qn, kn, vt);
  k_attn_part<<<dim3(80, 32), 256, 0, stream>>>(qkvg, vt, part, ml);
  k_attn_comb<<<dim3(32, 32), 256, 0, stream>>>(part, ml, qkvg, aws);
  k_gemm_out<<<dim3(16, 16), 256, 0, stream>>>(aws, wob, out);
}